// Round 2
// baseline (105.597 us; speedup 1.0000x reference)
//
#include <hip/hip_runtime.h>

#define NC    129            // lags 0..128
#define LLEN  8192
#define COM   (LLEN - 128)   // 8064
#define KT    16             // lag-tile stride
#define KOUT  17             // lags computed per block (tiles overlap by 1 lag)
#define NKT   8              // 8 tiles cover lags 0..128
#define BB    32
#define NBLOCKS (NKT * BB * 2)   // 512 = exactly 2 blocks/CU

// One fused kernel:
//  - each block computes S[sig][b][k0..k0+16] = sum_t (x[t]-mu)*x[t+k]
//    (the Y-side mean cancels because sum(x0c)=0; the 1/com cancels in S[k]/S[0])
//  - last block to finish (atomic counter) computes the loss and writes d_out.
__global__ __launch_bounds__(256)
void ac_fused_kernel(const float* __restrict__ fake, const float* __restrict__ real,
                     float* __restrict__ out, unsigned int* __restrict__ counter,
                     float* __restrict__ S) {
    __shared__ float sx[LLEN];     // full row; max read index proven <= 8191
    __shared__ float sred[4 * KOUT];
    __shared__ int lastFlag;

    const int tid   = threadIdx.x;
    const int ktile = blockIdx.x;          // 0..7
    const int b     = blockIdx.y;          // 0..31
    const int sig   = blockIdx.z;          // 0: fake, 1: real
    const float* x  = (sig == 0 ? fake : real) + (size_t)b * LLEN;

    // ---- stage row into LDS (float4, lane-contiguous = conflict-free) ----
    float psum = 0.f;
#pragma unroll
    for (int i = 0; i < 8; ++i) {
        int g = tid + 256 * i;                         // float4 index 0..2047
        float4 v = reinterpret_cast<const float4*>(x)[g];
        reinterpret_cast<float4*>(sx)[g] = v;
        if (g < COM / 4) psum += (v.x + v.y) + (v.z + v.w);
    }
    // mean of x[0:COM]: wave-64 butterfly + cross-wave via LDS
    for (int off = 1; off < 64; off <<= 1) psum += __shfl_xor(psum, off);
    if ((tid & 63) == 0) sred[tid >> 6] = psum;
    __syncthreads();
    const float mu = (sred[0] + sred[1] + sred[2] + sred[3]) * (1.0f / COM);

    // ---- sliding-window correlation: 17 lags per block ----
    const int k0 = ktile * KT;                         // 0,16,...,112 (4-aligned)
    float acc[KOUT];
#pragma unroll
    for (int k = 0; k < KOUT; ++k) acc[k] = 0.f;

#pragma unroll
    for (int i = 0; i < 8; ++i) {
        int g = tid + 256 * i;
        if (g < COM / 4) {
            float4 x0 = reinterpret_cast<const float4*>(sx)[g];
            const float c0 = x0.x - mu, c1 = x0.y - mu, c2 = x0.z - mu, c3 = x0.w - mu;
            float w[20];
            const int base = 4 * g + k0;               // 4-aligned; base+19 <= 8191
#pragma unroll
            for (int j = 0; j < 5; ++j) {
                float4 wv = *reinterpret_cast<const float4*>(&sx[base + 4 * j]);
                w[4 * j + 0] = wv.x; w[4 * j + 1] = wv.y;
                w[4 * j + 2] = wv.z; w[4 * j + 3] = wv.w;
            }
#pragma unroll
            for (int k = 0; k < KOUT; ++k) {
                float t0 = fmaf(c0, w[k + 0], acc[k]);
                t0       = fmaf(c1, w[k + 1], t0);
                t0       = fmaf(c2, w[k + 2], t0);
                acc[k]   = fmaf(c3, w[k + 3], t0);
            }
        }
    }

    // ---- block reduce each lag, write raw sums ----
#pragma unroll
    for (int k = 0; k < KOUT; ++k)
        for (int off = 1; off < 64; off <<= 1) acc[k] += __shfl_xor(acc[k], off);

    const int wave = tid >> 6, lane = tid & 63;
    __syncthreads();                                   // sred reuse
    if (lane == 0) {
#pragma unroll
        for (int k = 0; k < KOUT; ++k) sred[wave * KOUT + k] = acc[k];
    }
    __syncthreads();
    if (tid < KOUT) {
        float s = sred[tid] + sred[KOUT + tid] + sred[2 * KOUT + tid] + sred[3 * KOUT + tid];
        // lag tiles overlap by one lag; both writers store bitwise-identical values
        S[((size_t)sig * BB + b) * NC + k0 + tid] = s;
    }

    // ---- last-block-done: release S, bump counter ----
    __threadfence();                                   // device-scope release
    __syncthreads();
    if (tid == 0) {
        unsigned int old = atomicAdd(counter, 1u);     // device-scope by default
        lastFlag = (old == NBLOCKS - 1) ? 1 : 0;
    }
    __syncthreads();
    if (!lastFlag) return;

    // ---- last block: loss = mean |Sf[k]/Sf[0] - Sr[k]/Sr[0]| ----
    __threadfence();                                   // device-scope acquire
    const float* Sf = S;
    const float* Sr = S + (size_t)BB * NC;
    float a = 0.f;
    for (int idx = tid; idx < BB * NC; idx += 256) {
        int bb = idx / NC;
        int kk = idx - bb * NC;
        float fr = Sf[bb * NC + kk] / Sf[bb * NC];
        float rr = Sr[bb * NC + kk] / Sr[bb * NC];
        a += fabsf(fr - rr);
    }
    for (int off = 1; off < 64; off <<= 1) a += __shfl_xor(a, off);
    __syncthreads();                                   // sred reuse
    if ((tid & 63) == 0) sred[tid >> 6] = a;
    __syncthreads();
    if (tid == 0) out[0] = (sred[0] + sred[1] + sred[2] + sred[3]) * (1.0f / (BB * NC));
}

extern "C" void kernel_launch(void* const* d_in, const int* in_sizes, int n_in,
                              void* d_out, int out_size, void* d_ws, size_t ws_size,
                              hipStream_t stream) {
    const float* fake = (const float*)d_in[0];
    const float* real = (const float*)d_in[1];
    unsigned int* counter = (unsigned int*)d_ws;
    float* S = (float*)((char*)d_ws + 256);       // S[2][32][129], 33 KB
    float* out = (float*)d_out;

    hipMemsetAsync(d_ws, 0, 4, stream);           // zero the counter (capture-safe)
    dim3 grid(NKT, BB, 2);
    ac_fused_kernel<<<grid, 256, 0, stream>>>(fake, real, out, counter, S);
}

// Round 7
// 72.936 us; speedup vs baseline: 1.4478x; 1.4478x over previous
//
#include <hip/hip_runtime.h>

#define NC    129            // lags 0..128
#define LLEN  8192
#define COM   (LLEN - 128)   // 8064
#define KT    16             // lag-tile stride
#define KOUT  17             // lags per block (tiles overlap by 1; double-write is bitwise-identical)
#define NKT   8              // 8 tiles cover lags 0..128
#define BB    32

// Kernel 1: S[sig][b][k] = sum_t (x[t]-mu) * x[t+k], t in [0,COM)
// (Y-side mean cancels since sum(x0c)=0; 1/com cancels in S[k]/S[0].)
__global__ __launch_bounds__(256)
void ac_sums_kernel(const float* __restrict__ fake, const float* __restrict__ real,
                    float* __restrict__ S) {
    __shared__ float sx[LLEN];            // full row; max read index 8191 exactly
    __shared__ float pacc[256 * KOUT];    // per-thread partials, stride 17 (odd -> conflict-free)
    __shared__ float pred2[8 * KOUT];
    __shared__ float sred[4];

    const int tid   = threadIdx.x;
    const int ktile = blockIdx.x;          // 0..7
    const int b     = blockIdx.y;          // 0..31
    const int sig   = blockIdx.z;          // 0 fake, 1 real
    const float* x  = (sig == 0 ? fake : real) + (size_t)b * LLEN;

    // ---- stage row into LDS (float4, lane-contiguous = conflict-free) ----
    float psum = 0.f;
#pragma unroll
    for (int i = 0; i < 8; ++i) {
        int g = tid + 256 * i;                         // float4 index 0..2047
        float4 v = reinterpret_cast<const float4*>(x)[g];
        reinterpret_cast<float4*>(sx)[g] = v;
        if (g < COM / 4) psum += (v.x + v.y) + (v.z + v.w);
    }
    // mean of x[0:COM]: one wave butterfly per wave + cross-wave via LDS (cheap, once)
    for (int off = 1; off < 64; off <<= 1) psum += __shfl_xor(psum, off);
    if ((tid & 63) == 0) sred[tid >> 6] = psum;
    __syncthreads();
    const float mu = (sred[0] + sred[1] + sred[2] + sred[3]) * (1.0f / COM);

    // ---- sliding-window correlation: 17 lags, t4 register tile ----
    const int k0 = ktile * KT;
    float acc[KOUT];
#pragma unroll
    for (int k = 0; k < KOUT; ++k) acc[k] = 0.f;

#pragma unroll
    for (int i = 0; i < 8; ++i) {
        int g = tid + 256 * i;
        if (g < COM / 4) {
            float4 x0 = reinterpret_cast<const float4*>(sx)[g];
            const float c0 = x0.x - mu, c1 = x0.y - mu, c2 = x0.z - mu, c3 = x0.w - mu;
            float w[20];
            const int base = 4 * g + k0;               // 16B-aligned; base+19 <= 8191
#pragma unroll
            for (int j = 0; j < 5; ++j) {
                float4 wv = *reinterpret_cast<const float4*>(&sx[base + 4 * j]);
                w[4 * j + 0] = wv.x; w[4 * j + 1] = wv.y;
                w[4 * j + 2] = wv.z; w[4 * j + 3] = wv.w;
            }
#pragma unroll
            for (int k = 0; k < KOUT; ++k) {
                float t0 = fmaf(c0, w[k + 0], acc[k]);
                t0       = fmaf(c1, w[k + 1], t0);
                t0       = fmaf(c2, w[k + 2], t0);
                acc[k]   = fmaf(c3, w[k + 3], t0);
            }
        }
    }

    // ---- shuffle-free block reduction: LDS transpose, 2 stages ----
#pragma unroll
    for (int k = 0; k < KOUT; ++k) pacc[tid * KOUT + k] = acc[k];   // stride 17: conflict-free
    __syncthreads();

    if (tid < 8 * KOUT) {                  // 136 threads: each sums 32 rows for one lag
        const int g = tid / KOUT;          // 0..7
        const int k = tid - g * KOUT;      // 0..16
        float s = 0.f;
        const int base = g * 32 * KOUT + k;
#pragma unroll
        for (int r = 0; r < 32; ++r) s += pacc[base + r * KOUT];
        pred2[g * KOUT + k] = s;
    }
    __syncthreads();

    if (tid < KOUT) {                      // 17 threads: final 8-way sum + store
        float s = 0.f;
#pragma unroll
        for (int g = 0; g < 8; ++g) s += pred2[g * KOUT + tid];
        S[((size_t)sig * BB + b) * NC + k0 + tid] = s;
    }
}

// Kernel 2: out = mean_{b,k} | Sf[b,k]/Sf[b,0] - Sr[b,k]/Sr[b,0] |
__global__ __launch_bounds__(256) void loss_kernel(const float* __restrict__ S,
                                                   float* __restrict__ out) {
    __shared__ float sred[4];
    const float* Sf = S;
    const float* Sr = S + (size_t)BB * NC;
    const int tid = threadIdx.x;

    float a = 0.f;
    for (int idx = tid; idx < BB * NC; idx += 256) {
        int bb = idx / NC;
        int kk = idx - bb * NC;
        float fr = Sf[bb * NC + kk] / Sf[bb * NC];
        float rr = Sr[bb * NC + kk] / Sr[bb * NC];
        a += fabsf(fr - rr);
    }
    for (int off = 1; off < 64; off <<= 1) a += __shfl_xor(a, off);
    if ((tid & 63) == 0) sred[tid >> 6] = a;
    __syncthreads();
    if (tid == 0) out[0] = (sred[0] + sred[1] + sred[2] + sred[3]) * (1.0f / (BB * NC));
}

extern "C" void kernel_launch(void* const* d_in, const int* in_sizes, int n_in,
                              void* d_out, int out_size, void* d_ws, size_t ws_size,
                              hipStream_t stream) {
    const float* fake = (const float*)d_in[0];
    const float* real = (const float*)d_in[1];
    float* S = (float*)d_ws;                       // S[2][32][129] = 33 KB
    float* out = (float*)d_out;

    dim3 grid(NKT, BB, 2);
    ac_sums_kernel<<<grid, 256, 0, stream>>>(fake, real, S);
    loss_kernel<<<1, 256, 0, stream>>>(S, out);
}